// Round 7
// baseline (126.475 us; speedup 1.0000x reference)
//
#include <hip/hip_runtime.h>

// Problem constants (reference: N=4, T=128, F=512, EMBED=128, NLOC=360)
#define NT 512    // N*T
#define FD 512    // F (freq bins / q positions)
#define ED 128    // EMBED
#define LD 360    // NLOC

typedef float f32x4 __attribute__((ext_vector_type(4)));  // nontemporal-builtin-compatible

// ---------------------------------------------------------------------------
// Algebraic fact: einsum("neqk,ntve->ntqe", attention, values) has no shared
// contraction index between its operands: softmax over k sums to 1, so
//   out[n,t,q,:] = Wo @ (Wv @ sum_v value[n,t,v,:]) + bo, independent of q,
//   query, key, Wq, Wk.  (Validated rounds 1-6; absmax 0.125 << 0.76.)
//
// History: R3 fused single-pass = 112.4 us (best). R5 redundant-read overlap
// = 170 us (XCD L2s not shared -> +384 MB HBM). R6 2-tile pipeline = 120 us
// (half the blocks -> less TLP; no overlap win). This round: R3 EXACTLY, one
// variable changed — nontemporal load/store hints so the 377 MB write stream
// doesn't write-allocate/double-move through L2 and the 128 MB zero-reuse
// read stream doesn't pollute it.
// ---------------------------------------------------------------------------

__global__ __launch_bounds__(512) void fused_attn(
    const float* __restrict__ value,   // [NT][FD][ED]
    const float* __restrict__ Wv,      // [ED][ED]  (row e, col c)
    const float* __restrict__ Wo,      // [LD][ED]  (row l, col e)
    const float* __restrict__ bo,      // [LD]
    float* __restrict__ out)           // [NT][FD][LD]
{
    const int nt  = blockIdx.x;
    const int tid = threadIdx.x;

    __shared__ float sRed[16][ED];   // 8 KB partial v-sums
    __shared__ float sS[ED];         // S[c] = sum_v value[nt][v][c]
    __shared__ float sP[ED];         // P[e] = <Wv[e,:], S>
    __shared__ float sG[LD];         // G[l] = <Wo[l,:], P> + bo[l]

    // ---- Phase 1: v-reduction (256 KB, nontemporal streaming reads) ----
    const int c4 = (tid & 31) * 4;   // f32 column group within a 512-B row
    const int vg = tid >> 5;         // 0..15 row subgroup
    const float* base = value + (size_t)nt * FD * ED;

    f32x4 acc = (f32x4)(0.f);
    #pragma unroll 8
    for (int i = 0; i < 32; ++i) {   // rows vg, vg+16, ..., vg+496
        const f32x4 r = __builtin_nontemporal_load(
            (const f32x4*)&base[(size_t)(vg + 16 * i) * ED + c4]);
        acc += r;
    }
    *(f32x4*)&sRed[vg][c4] = acc;
    __syncthreads();

    if (tid < ED) {
        float s = 0.f;
        #pragma unroll
        for (int g = 0; g < 16; ++g) s += sRed[g][tid];
        sS[tid] = s;
    }
    __syncthreads();

    // ---- Phase 2: P = Wv * S  (Wv 64 KB, L2-resident) ----
    if (tid < ED) {
        const float* wr = Wv + (size_t)tid * ED;
        float p = 0.f;
        #pragma unroll
        for (int c = 0; c < ED; c += 4) {
            const float4 w4 = *(const float4*)&wr[c];
            const float4 s4 = *(const float4*)&sS[c];
            p += w4.x * s4.x + w4.y * s4.y + w4.z * s4.z + w4.w * s4.w;
        }
        sP[tid] = p;
    }
    __syncthreads();

    // ---- Phase 3: G = Wo * P + bo  (360 <= 512: one pass) ----
    if (tid < LD) {
        const float* wr = Wo + (size_t)tid * ED;
        float g = bo[tid];
        #pragma unroll
        for (int e = 0; e < ED; e += 4) {
            const float4 w4 = *(const float4*)&wr[e];
            const float4 p4 = *(const float4*)&sP[e];
            g += w4.x * p4.x + w4.y * p4.y + w4.z * p4.z + w4.w * p4.w;
        }
        sG[tid] = g;
    }
    __syncthreads();

    // ---- Phase 4: broadcast 512 rows x 1440 B (720 KB, nontemporal stores) ----
    const int wave = tid >> 6;       // 0..7
    const int lane = tid & 63;
    const f32x4* sG4 = (const f32x4*)sG;        // 90 vec4
    f32x4 rA = sG4[lane];
    f32x4 rB = (f32x4)(0.f);
    if (lane < 26) rB = sG4[64 + lane];

    float* obase = out + (size_t)nt * FD * LD;
    #pragma unroll 4
    for (int r = wave; r < FD; r += 8) {        // 64 rows per wave
        f32x4* row = (f32x4*)(obase + (size_t)r * LD);
        __builtin_nontemporal_store(rA, &row[lane]);          // 1024 B contiguous
        if (lane < 26)
            __builtin_nontemporal_store(rB, &row[64 + lane]); // 416 B contiguous
    }
}

extern "C" void kernel_launch(void* const* d_in, const int* in_sizes, int n_in,
                              void* d_out, int out_size, void* d_ws, size_t ws_size,
                              hipStream_t stream) {
    (void)in_sizes; (void)n_in; (void)out_size; (void)d_ws; (void)ws_size;
    // setup_inputs order: value, key, query, Wv, Wk, Wq, Wo, bo
    const float* value = (const float*)d_in[0];
    const float* Wv    = (const float*)d_in[3];
    const float* Wo    = (const float*)d_in[6];
    const float* bo    = (const float*)d_in[7];
    float* out = (float*)d_out;

    fused_attn<<<dim3(NT), dim3(512), 0, stream>>>(value, Wv, Wo, bo, out);
}

// Round 8
// 120.924 us; speedup vs baseline: 1.0459x; 1.0459x over previous
//
#include <hip/hip_runtime.h>

// Problem constants (reference: N=4, T=128, F=512, EMBED=128, NLOC=360)
#define NT 512    // N*T
#define FD 512    // F (freq bins / q positions)
#define ED 128    // EMBED
#define LD 360    // NLOC

// ---------------------------------------------------------------------------
// Algebraic fact: einsum("neqk,ntve->ntqe", attention, values) has no shared
// contraction index between its operands: softmax over k sums to 1, so
//   out[n,t,q,:] = Wo @ (Wv @ sum_v value[n,t,v,:]) + bo, independent of q,
//   query, key, Wq, Wk.  (Validated rounds 1-7; absmax 0.125 << 0.76.)
//
// History: R3 fused = 112.4 us (control). R5 redundant reads = 170 (XCD L2
// miss). R6 2-tile pipeline = 120 (TLP loss). R7 nontemporal = 126.5 (L2
// write-combining needed for 1440-B rows). Fitting R1+R3: phases run at
// ~5.2-5.5 TB/s (mixed read/write stream turnaround), fills hit 6.9 pure.
// This round: split directions globally — kernel A pure-read (value -> G in
// ws), kernel B pure-write (G -> out, fill-like grid). If mixed-stream was
// the cost: ~95-105 us. If >=110: node overhead dominates, R3 is optimal.
// ---------------------------------------------------------------------------

// Kernel A: pure read. One block per nt: reduce 512 v-rows, project via Wv
// then Wo (+bo), write G[nt][LD] to workspace. HBM: 128 MB read, 737 KB write.
__global__ __launch_bounds__(512) void kA_read_project(
    const float* __restrict__ value,   // [NT][FD][ED]
    const float* __restrict__ Wv,      // [ED][ED]
    const float* __restrict__ Wo,      // [LD][ED]
    const float* __restrict__ bo,      // [LD]
    float* __restrict__ G)             // [NT][LD]
{
    const int nt  = blockIdx.x;
    const int tid = threadIdx.x;

    __shared__ float sRed[16][ED];   // 8 KB
    __shared__ float sS[ED];
    __shared__ float sP[ED];

    const int c4 = (tid & 31) * 4;
    const int vg = tid >> 5;         // 0..15
    const float* base = value + (size_t)nt * FD * ED;

    float4 acc; acc.x = 0.f; acc.y = 0.f; acc.z = 0.f; acc.w = 0.f;
    #pragma unroll 8
    for (int i = 0; i < 32; ++i) {   // rows vg, vg+16, ..., vg+496
        const float4 r = *(const float4*)&base[(size_t)(vg + 16 * i) * ED + c4];
        acc.x += r.x; acc.y += r.y; acc.z += r.z; acc.w += r.w;
    }
    *(float4*)&sRed[vg][c4] = acc;
    __syncthreads();

    if (tid < ED) {
        float s = 0.f;
        #pragma unroll
        for (int g = 0; g < 16; ++g) s += sRed[g][tid];
        sS[tid] = s;
    }
    __syncthreads();

    if (tid < ED) {
        const float* wr = Wv + (size_t)tid * ED;
        float p = 0.f;
        #pragma unroll
        for (int c = 0; c < ED; c += 4) {
            const float4 w4 = *(const float4*)&wr[c];
            const float4 s4 = *(const float4*)&sS[c];
            p += w4.x * s4.x + w4.y * s4.y + w4.z * s4.z + w4.w * s4.w;
        }
        sP[tid] = p;
    }
    __syncthreads();

    if (tid < LD) {
        const float* wr = Wo + (size_t)tid * ED;
        float g = bo[tid];
        #pragma unroll
        for (int e = 0; e < ED; e += 4) {
            const float4 w4 = *(const float4*)&wr[e];
            const float4 p4 = *(const float4*)&sP[e];
            g += w4.x * p4.x + w4.y * p4.y + w4.z * p4.z + w4.w * p4.w;
        }
        G[(size_t)nt * LD + tid] = g;
    }
}

// Kernel B: pure write, fill-like. Grid (8, 512) x 256 threads: block (qc,nt)
// broadcasts G[nt] into 64 output rows. G rows are L2/LLC-hot (8x reuse,
// adjacent dispatch). HBM: 377 MB write.
__global__ __launch_bounds__(256) void kB_broadcast(
    const float* __restrict__ G,       // [NT][LD]
    float* __restrict__ out)           // [NT][FD][LD]
{
    const int qc  = blockIdx.x;   // 0..7
    const int nt  = blockIdx.y;   // 0..511
    const int tid = threadIdx.x;

    __shared__ float sG[LD];
    if (tid < LD) sG[tid] = G[(size_t)nt * LD + tid];
    if (tid + 256 < LD) sG[tid + 256] = G[(size_t)nt * LD + tid + 256];
    __syncthreads();

    const int wave = tid >> 6;    // 0..3
    const int lane = tid & 63;
    const float4* sG4 = (const float4*)sG;      // 90 float4
    float4 rA = sG4[lane];
    float4 rB; rB.x = 0.f; rB.y = 0.f; rB.z = 0.f; rB.w = 0.f;
    if (lane < 26) rB = sG4[64 + lane];

    float* obase = out + ((size_t)nt * FD + (size_t)qc * 64) * LD;
    #pragma unroll 4
    for (int r = wave; r < 64; r += 4) {        // 16 rows per wave
        float4* row = (float4*)(obase + (size_t)r * LD);
        row[lane] = rA;                          // 1024 B contiguous
        if (lane < 26) row[64 + lane] = rB;      // 416 B contiguous
    }
}

extern "C" void kernel_launch(void* const* d_in, const int* in_sizes, int n_in,
                              void* d_out, int out_size, void* d_ws, size_t ws_size,
                              hipStream_t stream) {
    (void)in_sizes; (void)n_in; (void)out_size; (void)ws_size;
    // setup_inputs order: value, key, query, Wv, Wk, Wq, Wo, bo
    const float* value = (const float*)d_in[0];
    const float* Wv    = (const float*)d_in[3];
    const float* Wo    = (const float*)d_in[6];
    const float* bo    = (const float*)d_in[7];
    float* out = (float*)d_out;
    float* G   = (float*)d_ws;    // NT*LD*4 = 737,280 bytes

    kA_read_project<<<dim3(NT), dim3(512), 0, stream>>>(value, Wv, Wo, bo, G);
    kB_broadcast<<<dim3(8, NT), dim3(256), 0, stream>>>(G, out);
}

// Round 9
// 116.903 us; speedup vs baseline: 1.0819x; 1.0344x over previous
//
#include <hip/hip_runtime.h>

// Problem constants (reference: N=4, T=128, F=512, EMBED=128, NLOC=360)
#define NT 512    // N*T
#define FD 512    // F (freq bins / q positions)
#define ED 128    // EMBED
#define LD 360    // NLOC

// ---------------------------------------------------------------------------
// Algebraic fact: einsum("neqk,ntve->ntqe", attention, values) has no shared
// contraction index between its operands: softmax over k sums to 1, so
//   out[n,t,q,:] = Wo @ (Wv @ sum_v value[n,t,v,:]) + bo, independent of q,
//   query, key, Wq, Wk.  (Validated rounds 1-8; absmax 0.125 << 0.76.)
//
// History: R3 fused 512thr = 112.4 us (control). R5 redundant reads = 170.
// R6 2-tile/256blk = 120. R7 nontemporal = 126.5. R8 pure-dir split = 120.9.
// Fit across R1/R3/R8: dur ~= 103 + 9.3*(#kernels) -> mixed-stream is NOT
// the cost; ~25 us systematic residual over the 80 us traffic floor.
// This round, single variable: block geometry 512thr/2-per-CU ->
// 1024thr/1-per-CU (same 16 waves/CU) so 512 blocks form TWO sequential
// generations: gen-2 reads backfill gen-1 write tails per-CU, and phase
// boundaries desynchronize instead of idling HBM in lockstep.
// ---------------------------------------------------------------------------

__global__ __launch_bounds__(1024) void fused_attn(
    const float* __restrict__ value,   // [NT][FD][ED]
    const float* __restrict__ Wv,      // [ED][ED]  (row e, col c)
    const float* __restrict__ Wo,      // [LD][ED]  (row l, col e)
    const float* __restrict__ bo,      // [LD]
    float* __restrict__ out)           // [NT][FD][LD]
{
    const int nt  = blockIdx.x;
    const int tid = threadIdx.x;

    __shared__ float sRed[32][ED];   // 16 KB partial v-sums
    __shared__ float sS[ED];         // S[c] = sum_v value[nt][v][c]
    __shared__ float sP[ED];         // P[e] = <Wv[e,:], S>
    __shared__ float sG[LD];         // G[l] = <Wo[l,:], P> + bo[l]

    // ---- Phase 1: v-reduction (256 KB, coalesced: each wave = 1 KB/issue) ----
    const int c4 = (tid & 31) * 4;   // f32 column group within a 512-B row
    const int vg = tid >> 5;         // 0..31 row subgroup
    const float* base = value + (size_t)nt * FD * ED;

    float4 acc; acc.x = 0.f; acc.y = 0.f; acc.z = 0.f; acc.w = 0.f;
    #pragma unroll 8
    for (int i = 0; i < 16; ++i) {   // rows vg, vg+32, ..., vg+480
        const float4 r = *(const float4*)&base[(size_t)(vg + 32 * i) * ED + c4];
        acc.x += r.x; acc.y += r.y; acc.z += r.z; acc.w += r.w;
    }
    *(float4*)&sRed[vg][c4] = acc;
    __syncthreads();

    if (tid < ED) {
        float s = 0.f;
        #pragma unroll
        for (int g = 0; g < 32; ++g) s += sRed[g][tid];
        sS[tid] = s;
    }
    __syncthreads();

    // ---- Phase 2: P = Wv * S  (Wv 64 KB, L2-resident) ----
    if (tid < ED) {
        const float* wr = Wv + (size_t)tid * ED;
        float p = 0.f;
        #pragma unroll
        for (int c = 0; c < ED; c += 4) {
            const float4 w4 = *(const float4*)&wr[c];
            const float4 s4 = *(const float4*)&sS[c];
            p += w4.x * s4.x + w4.y * s4.y + w4.z * s4.z + w4.w * s4.w;
        }
        sP[tid] = p;
    }
    __syncthreads();

    // ---- Phase 3: G = Wo * P + bo ----
    if (tid < LD) {
        const float* wr = Wo + (size_t)tid * ED;
        float g = bo[tid];
        #pragma unroll
        for (int e = 0; e < ED; e += 4) {
            const float4 w4 = *(const float4*)&wr[e];
            const float4 p4 = *(const float4*)&sP[e];
            g += w4.x * p4.x + w4.y * p4.y + w4.z * p4.z + w4.w * p4.w;
        }
        sG[tid] = g;
    }
    __syncthreads();

    // ---- Phase 4: broadcast 512 rows x 1440 B (720 KB, register-sourced) ----
    const int wave = tid >> 6;       // 0..15
    const int lane = tid & 63;
    const float4* sG4 = (const float4*)sG;      // 90 float4
    float4 rA = sG4[lane];
    float4 rB; rB.x = 0.f; rB.y = 0.f; rB.z = 0.f; rB.w = 0.f;
    if (lane < 26) rB = sG4[64 + lane];

    float* obase = out + (size_t)nt * FD * LD;
    #pragma unroll 4
    for (int r = wave; r < FD; r += 16) {       // 32 rows per wave
        float4* row = (float4*)(obase + (size_t)r * LD);
        row[lane] = rA;                          // 1024 B contiguous
        if (lane < 26) row[64 + lane] = rB;      // 416 B contiguous
    }
}

extern "C" void kernel_launch(void* const* d_in, const int* in_sizes, int n_in,
                              void* d_out, int out_size, void* d_ws, size_t ws_size,
                              hipStream_t stream) {
    (void)in_sizes; (void)n_in; (void)out_size; (void)d_ws; (void)ws_size;
    // setup_inputs order: value, key, query, Wv, Wk, Wq, Wo, bo
    const float* value = (const float*)d_in[0];
    const float* Wv    = (const float*)d_in[3];
    const float* Wo    = (const float*)d_in[6];
    const float* bo    = (const float*)d_in[7];
    float* out = (float*)d_out;

    fused_attn<<<dim3(NT), dim3(1024), 0, stream>>>(value, Wv, Wo, bo, out);
}

// Round 10
// 112.480 us; speedup vs baseline: 1.1244x; 1.0393x over previous
//
#include <hip/hip_runtime.h>

// Problem constants (reference: N=4, T=128, F=512, EMBED=128, NLOC=360)
#define NT 512    // N*T
#define FD 512    // F (freq bins / q positions)
#define ED 128    // EMBED
#define LD 360    // NLOC

// ---------------------------------------------------------------------------
// Algebraic fact: einsum("neqk,ntve->ntqe", attention, values) has no shared
// contraction index between its operands: softmax over k sums to 1, so
//   out[n,t,q,:] = Wo @ (Wv @ sum_v value[n,t,v,:]) + bo, independent of q,
//   query, key, Wq, Wk.  (Validated rounds 1-9; absmax 0.125 << 0.76.)
//
// FINAL: this is the R3 kernel (112.4 us), the best of 7 structures tested:
//   R3  fused, 512 blk x 512 thr, bulk-sync ................ 112.4  <- best
//   R9  1024 thr / 1 blk per CU ............................ 116.9
//   R6  2-tile software pipeline, 256 blk .................. 120.0
//   R8  pure-read kernel + pure-write kernel ............... 120.9
//   R7  R3 + nontemporal hints ............................. 126.5
//   R1  3-kernel split ..................................... 130.4
//   R5  redundant-read overlap (XCD L2 non-shared) ......... 169.9
// Accounting: 505 MB mandatory traffic @ ~6.9 TB/s pure-stream = ~73 us;
// measured kernel ~102 us (mixed-stream + phase-boundary ramp, all
// structures pay it) + ~10 us fixed dispatch/graph overhead. All structural
// levers tested regress; this is the effective roofline for this op here.
// ---------------------------------------------------------------------------

__global__ __launch_bounds__(512) void fused_attn(
    const float* __restrict__ value,   // [NT][FD][ED]
    const float* __restrict__ Wv,      // [ED][ED]  (row e, col c)
    const float* __restrict__ Wo,      // [LD][ED]  (row l, col e)
    const float* __restrict__ bo,      // [LD]
    float* __restrict__ out)           // [NT][FD][LD]
{
    const int nt  = blockIdx.x;
    const int tid = threadIdx.x;

    __shared__ float sRed[16][ED];   // 8 KB partial v-sums
    __shared__ float sS[ED];         // S[c] = sum_v value[nt][v][c]
    __shared__ float sP[ED];         // P[e] = <Wv[e,:], S>
    __shared__ float sG[LD];         // G[l] = <Wo[l,:], P> + bo[l]

    // ---- Phase 1: v-reduction (read 256 KB, fully coalesced) ----
    const int c4 = (tid & 31) * 4;   // f32 column group within a 512-B row
    const int vg = tid >> 5;         // 0..15 row subgroup
    const float* base = value + (size_t)nt * FD * ED;

    float4 acc; acc.x = 0.f; acc.y = 0.f; acc.z = 0.f; acc.w = 0.f;
    #pragma unroll 8
    for (int i = 0; i < 32; ++i) {   // rows vg, vg+16, ..., vg+496
        const float4 r = *(const float4*)&base[(size_t)(vg + 16 * i) * ED + c4];
        acc.x += r.x; acc.y += r.y; acc.z += r.z; acc.w += r.w;
    }
    *(float4*)&sRed[vg][c4] = acc;
    __syncthreads();

    if (tid < ED) {
        float s = 0.f;
        #pragma unroll
        for (int g = 0; g < 16; ++g) s += sRed[g][tid];
        sS[tid] = s;
    }
    __syncthreads();

    // ---- Phase 2: P = Wv * S  (Wv 64 KB, L2-resident across blocks) ----
    if (tid < ED) {
        const float* wr = Wv + (size_t)tid * ED;
        float p = 0.f;
        #pragma unroll
        for (int c = 0; c < ED; c += 4) {
            const float4 w4 = *(const float4*)&wr[c];
            const float4 s4 = *(const float4*)&sS[c];
            p += w4.x * s4.x + w4.y * s4.y + w4.z * s4.z + w4.w * s4.w;
        }
        sP[tid] = p;
    }
    __syncthreads();

    // ---- Phase 3: G = Wo * P + bo  (360 <= 512: one pass) ----
    if (tid < LD) {
        const float* wr = Wo + (size_t)tid * ED;
        float g = bo[tid];
        #pragma unroll
        for (int e = 0; e < ED; e += 4) {
            const float4 w4 = *(const float4*)&wr[e];
            const float4 p4 = *(const float4*)&sP[e];
            g += w4.x * p4.x + w4.y * p4.y + w4.z * p4.z + w4.w * p4.w;
        }
        sG[tid] = g;
    }
    __syncthreads();

    // ---- Phase 4: broadcast-store 512 rows x 1440 B (720 KB, pure stores) ----
    // Row image lives in registers: slot `lane` (rA) + slot `64+lane` (rB).
    const int wave = tid >> 6;       // 0..7
    const int lane = tid & 63;
    const float4* sG4 = (const float4*)sG;      // 90 float4
    float4 rA = sG4[lane];
    float4 rB; rB.x = 0.f; rB.y = 0.f; rB.z = 0.f; rB.w = 0.f;
    if (lane < 26) rB = sG4[64 + lane];

    float* obase = out + (size_t)nt * FD * LD;
    for (int r = wave; r < FD; r += 8) {        // 64 rows per wave
        float4* row = (float4*)(obase + (size_t)r * LD);
        row[lane] = rA;                          // 1024 B contiguous
        if (lane < 26) row[64 + lane] = rB;      // 416 B contiguous
    }
}

extern "C" void kernel_launch(void* const* d_in, const int* in_sizes, int n_in,
                              void* d_out, int out_size, void* d_ws, size_t ws_size,
                              hipStream_t stream) {
    (void)in_sizes; (void)n_in; (void)out_size; (void)d_ws; (void)ws_size;
    // setup_inputs order: value, key, query, Wv, Wk, Wq, Wo, bo
    const float* value = (const float*)d_in[0];
    const float* Wv    = (const float*)d_in[3];
    const float* Wo    = (const float*)d_in[6];
    const float* bo    = (const float*)d_in[7];
    float* out = (float*)d_out;

    fused_attn<<<dim3(NT), dim3(512), 0, stream>>>(value, Wv, Wo, bo, out);
}